// Round 8
// baseline (1563.784 us; speedup 1.0000x reference)
//
#include <hip/hip_runtime.h>
#include <hip/hip_bf16.h>
#include <stdint.h>

// GAT v4: 4-kernel pipeline.
//   k_gemm_s: f32 tile GEMM -> bf16 z, with fused per-head score epilogue
//   k_init:   seed bucket cursors (static over-allocated bucket regions)
//   k_bin2:   bin edges by 64-node dst bucket (LDS count -> reserve -> scatter)
//   k_agg:    per-bucket LDS f32-atomic aggregation + normalize (no fine CSR!)
// N=50000, E=1.6M, IN=128, OUT=32, H=4 (H*O=128)
// (Resubmission: round-7 bench died on container failure, kernel never ran.)

#define NN 50000
#define NE 1600000
#define IN_DIM 128
#define OC 128
#define NBSH 6
#define NBUCK ((NN + 63) >> 6)   // 782 buckets of 64 dst nodes
#define CAP 2560                 // bucket capacity: mean 2046 + 11 sigma
#define CURS 16                  // cursor stride (ints) = 64 B padding
#define BIN_BLOCKS 256
#define EPB ((NE + BIN_BLOCKS - 1) / BIN_BLOCKS)   // 6250 edges per bin block
#define RPITCH 132               // LDS row pitch in dwords (128 + 4 pad)

__device__ __forceinline__ float lrelu(float x) { return x >= 0.f ? x : 0.01f * x; }

// ------------------------------------------- projection + fused score tables
// z = h @ Wc^T (f32 accum, bf16 out). Epilogue: s_src/s_dst via half-wave shfl.
__global__ __launch_bounds__(256) void k_gemm_s(const float* __restrict__ h,
                                                const float* __restrict__ W,
                                                const float* __restrict__ a,
                                                __hip_bfloat16* __restrict__ zb,
                                                float* __restrict__ ssrc,
                                                float* __restrict__ sdst) {
    __shared__ float hs[64][65];
    __shared__ float ws[64][129];
    const int t  = threadIdx.x;
    const int n0 = blockIdx.x * 64;
    const int tx = t & 31;   // channel base: c = tx + 32*j  (head j, pos tx)
    const int ty = t >> 5;   // node base:    n = ty + 8*i

    float acc[8][4];
#pragma unroll
    for (int i = 0; i < 8; ++i)
#pragma unroll
        for (int j = 0; j < 4; ++j) acc[i][j] = 0.f;

    for (int kt = 0; kt < IN_DIM; kt += 64) {
#pragma unroll
        for (int s = 0; s < 4; ++s) {
            const int idx4 = t + s * 256;
            const int n    = idx4 >> 4;
            const int kk   = (idx4 & 15) << 2;
            const int gn   = n0 + n;
            float4 v = make_float4(0.f, 0.f, 0.f, 0.f);
            if (gn < NN) v = *(const float4*)(h + (size_t)gn * IN_DIM + kt + kk);
            hs[kk + 0][n] = v.x; hs[kk + 1][n] = v.y;
            hs[kk + 2][n] = v.z; hs[kk + 3][n] = v.w;
        }
#pragma unroll
        for (int s = 0; s < 8; ++s) {
            const int idx4 = t + s * 256;
            const int c    = idx4 >> 4;
            const int kk   = (idx4 & 15) << 2;
            const float4 v = *(const float4*)(W + (size_t)c * IN_DIM + kt + kk);
            ws[kk + 0][c] = v.x; ws[kk + 1][c] = v.y;
            ws[kk + 2][c] = v.z; ws[kk + 3][c] = v.w;
        }
        __syncthreads();
#pragma unroll 4
        for (int k = 0; k < 64; ++k) {
            float wv[4], hv[8];
#pragma unroll
            for (int j = 0; j < 4; ++j) wv[j] = ws[k][tx + 32 * j];
#pragma unroll
            for (int i = 0; i < 8; ++i) hv[i] = hs[k][ty + 8 * i];
#pragma unroll
            for (int i = 0; i < 8; ++i)
#pragma unroll
                for (int j = 0; j < 4; ++j) acc[i][j] = fmaf(hv[i], wv[j], acc[i][j]);
        }
        __syncthreads();
    }
    // z out (bf16)
#pragma unroll
    for (int i = 0; i < 8; ++i) {
        const int gn = n0 + ty + 8 * i;
        if (gn < NN) {
#pragma unroll
            for (int j = 0; j < 4; ++j)
                zb[(size_t)gn * OC + tx + 32 * j] = __float2bfloat16(acc[i][j]);
        }
    }
    // fused scores: s_src[n][j] = sum_tx acc[i][j]*a[j*64+tx]; dst uses a[...+32]
    float as[4], ad[4];
#pragma unroll
    for (int j = 0; j < 4; ++j) {
        as[j] = a[j * 64 + tx];
        ad[j] = a[j * 64 + 32 + tx];
    }
#pragma unroll
    for (int i = 0; i < 8; ++i) {
        const int gn = n0 + ty + 8 * i;
#pragma unroll
        for (int j = 0; j < 4; ++j) {
            float ps = acc[i][j] * as[j];
            float pd = acc[i][j] * ad[j];
#pragma unroll
            for (int off = 16; off > 0; off >>= 1) {
                ps += __shfl_xor(ps, off);
                pd += __shfl_xor(pd, off);
            }
            if (tx == 0 && gn < NN) {
                ssrc[gn * 4 + j] = ps;
                sdst[gn * 4 + j] = pd;
            }
        }
    }
}

// ------------------------------------------------------ seed bucket cursors
__global__ __launch_bounds__(256) void k_init(int* __restrict__ cursor) {
    const int b = blockIdx.x * 256 + threadIdx.x;
    if (b < NBUCK) cursor[b * CURS] = b * CAP;
}

// ------------------- bin edges: LDS count -> per-(block,bucket) reserve -> scatter
__global__ __launch_bounds__(256) void k_bin2(const int* __restrict__ src,
                                              const int* __restrict__ dst,
                                              int* __restrict__ cursor,
                                              uint32_t* __restrict__ ebuf) {
    __shared__ int hb[NBUCK];
    __shared__ int ofs[NBUCK];
    const int t    = threadIdx.x;
    const int ebeg = blockIdx.x * EPB;
    const int eend = min(ebeg + EPB, NE);
    for (int i = t; i < NBUCK; i += 256) hb[i] = 0;
    __syncthreads();
    for (int e = ebeg + t; e < eend; e += 256)
        atomicAdd(&hb[dst[e] >> NBSH], 1);
    __syncthreads();
    for (int i = t; i < NBUCK; i += 256) {
        const int c = hb[i];
        ofs[i] = (c > 0) ? atomicAdd(&cursor[i * CURS], c) : 0;
        hb[i] = 0;
    }
    __syncthreads();
    for (int e = ebeg + t; e < eend; e += 256) {
        const int d = dst[e];
        const int b = d >> NBSH;
        const int p = ofs[b] + atomicAdd(&hb[b], 1);
        if (p < (b + 1) * CAP)   // defensive (statistically impossible overflow)
            ebuf[p] = (uint32_t)src[e] | ((uint32_t)(d & 63) << 16);
    }
}

// ----------------------------------- per-bucket LDS-atomic aggregate + normalize
// 512 threads (8 waves). 16-lane group g handles edge it*32+g; lane16 covers
// channels [8*lane16, 8*lane16+8) via one dwordx4 from zb. Accumulate into
// permuted LDS tile: ch c -> dword ((c&15)<<3)|(c>>4), row pitch 132.
// For lane16 l, dword q, lo/hi: idx = dl*132 + 64*(l&1) + (l>>1) + 16q + 8*hi.
__global__ __launch_bounds__(512) void k_agg(const uint32_t* __restrict__ zb,
                                             const float* __restrict__ ssrc,
                                             const float* __restrict__ sdst,
                                             const int* __restrict__ cursor,
                                             const uint32_t* __restrict__ ebuf,
                                             float* __restrict__ out) {
    __shared__ float tile[64 * RPITCH];   // 33792 B
    __shared__ float dnl[64 * 4];         //  1024 B
    __shared__ float sdl[64 * 4];         //  1024 B
    const int b      = blockIdx.x;
    const int tid    = threadIdx.x;
    const int lane16 = tid & 15;
    const int g      = tid >> 4;          // 0..31 edge-group across block
    const int hsel   = lane16 >> 2;
    const int bbase  = b * CAP;
    int bend = cursor[b * CURS];
    bend = min(bend, bbase + CAP);
    const int cnt = bend - bbase;

    // zero accumulators, stage sdst tile
    for (int i = tid; i < 64 * RPITCH; i += 512) tile[i] = 0.f;
    if (tid < 256) {
        const int gnode = (b << NBSH) + (tid >> 2);
        dnl[tid] = 0.f;
        sdl[tid] = (gnode < NN) ? sdst[gnode * 4 + (tid & 3)] : 0.f;
    }
    __syncthreads();

    const int lbase = 64 * (lane16 & 1) + (lane16 >> 1);
    for (int e = g; e < cnt; e += 32) {
        const uint32_t v   = ebuf[bbase + e];
        const int      sid = v & 0xffffu;
        const int      dl  = (v >> 16) & 63;
        const float    ss  = ssrc[sid * 4 + hsel];
        const float    x   = __expf(lrelu(ss + sdl[dl * 4 + hsel]));
        if ((lane16 & 3) == 0) atomicAdd(&dnl[dl * 4 + hsel], x);
        const uint4 Z = *(const uint4*)(zb + ((size_t)sid << 6) + (lane16 << 2));
        float* rb = &tile[dl * RPITCH + lbase];
        atomicAdd(&rb[ 0], x * __builtin_bit_cast(float, Z.x << 16));
        atomicAdd(&rb[ 8], x * __builtin_bit_cast(float, Z.x & 0xffff0000u));
        atomicAdd(&rb[16], x * __builtin_bit_cast(float, Z.y << 16));
        atomicAdd(&rb[24], x * __builtin_bit_cast(float, Z.y & 0xffff0000u));
        atomicAdd(&rb[32], x * __builtin_bit_cast(float, Z.z << 16));
        atomicAdd(&rb[40], x * __builtin_bit_cast(float, Z.z & 0xffff0000u));
        atomicAdd(&rb[48], x * __builtin_bit_cast(float, Z.w << 16));
        atomicAdd(&rb[56], x * __builtin_bit_cast(float, Z.w & 0xffff0000u));
    }
    __syncthreads();

    // normalize + write: thread t -> node t>>3, channels (t&7)*16 + k
    const int nl    = tid >> 3;
    const int sub   = tid & 7;
    const int head  = sub >> 1;
    const int gnode = (b << NBSH) + nl;
    if (gnode < NN) {
        const float dn  = dnl[nl * 4 + head];
        const float inv = (dn > 0.f) ? 1.0f / dn : 0.f;
        float* op = out + (size_t)gnode * OC + (sub << 4);
        const float* rp = &tile[nl * RPITCH + sub];
        float4 o0, o1, o2, o3;
        o0.x = rp[  0] * inv; o0.y = rp[  8] * inv; o0.z = rp[ 16] * inv; o0.w = rp[ 24] * inv;
        o1.x = rp[ 32] * inv; o1.y = rp[ 40] * inv; o1.z = rp[ 48] * inv; o1.w = rp[ 56] * inv;
        o2.x = rp[ 64] * inv; o2.y = rp[ 72] * inv; o2.z = rp[ 80] * inv; o2.w = rp[ 88] * inv;
        o3.x = rp[ 96] * inv; o3.y = rp[104] * inv; o3.z = rp[112] * inv; o3.w = rp[120] * inv;
        *(float4*)(op +  0) = o0;
        *(float4*)(op +  4) = o1;
        *(float4*)(op +  8) = o2;
        *(float4*)(op + 12) = o3;
    }
}

// ------------------------------------------------------------------- launcher
extern "C" void kernel_launch(void* const* d_in, const int* in_sizes, int n_in,
                              void* d_out, int out_size, void* d_ws, size_t ws_size,
                              hipStream_t stream) {
    const float* h_in = (const float*)d_in[0];
    const float* W    = (const float*)d_in[1];
    const float* a    = (const float*)d_in[2];
    const int*   src  = (const int*)d_in[3];
    const int*   dst  = (const int*)d_in[4];
    float*       out  = (float*)d_out;

    char* w = (char*)d_ws;
    __hip_bfloat16* zb = (__hip_bfloat16*)(w);          // 12,800,000 B
    float*    ssrc     = (float*)(w + 12800000);        //    800,000 B
    float*    sdst     = (float*)(w + 13600000);        //    800,000 B
    int*      cursor   = (int*)(w + 14400000);          //     50,048 B
    uint32_t* ebuf     = (uint32_t*)(w + 14450048);     //  8,007,680 B (782*2560*4)
    // total 22,457,728 B

    k_gemm_s<<<(NN + 63) / 64, 256, 0, stream>>>(h_in, W, a, zb, ssrc, sdst);
    k_init  <<<(NBUCK + 255) / 256, 256, 0, stream>>>(cursor);
    k_bin2  <<<BIN_BLOCKS, 256, 0, stream>>>(src, dst, cursor, ebuf);
    k_agg   <<<NBUCK, 512, 0, stream>>>((const uint32_t*)zb, ssrc, sdst,
                                        cursor, ebuf, out);
}

// Round 9
// 235.792 us; speedup vs baseline: 6.6320x; 6.6320x over previous
//
#include <hip/hip_runtime.h>
#include <hip/hip_bf16.h>
#include <stdint.h>

// GAT v5: 4-kernel pipeline, register-accumulating gather (LDS atomics OFF the
// per-edge channel path — round-8 showed LDS f32 atomics run ~4 cy/lane-op).
//   k_gemm_s: f32 tile GEMM -> bf16 z + fused per-head score epilogue
//   k_init:   seed bucket cursors (static CAP bucket regions)
//   k_bin2:   bin edges by 64-node dst bucket (LDS count -> reserve -> scatter)
//   k_gatb:   per-bucket: LDS sort into per-node lists, then k_gat4-style
//             per-wave register accumulation (1 wave = 1 node, 8 nodes/wave)
// N=50000, E=1.6M, IN=128, OUT=32, H=4 (H*O=128)

#define NN 50000
#define NE 1600000
#define IN_DIM 128
#define OC 128
#define NBSH 6
#define NBUCK ((NN + 63) >> 6)   // 782 buckets of 64 dst nodes
#define CAP 2560                 // bucket capacity: mean 2046 + ~11 sigma
#define CURS 16                  // cursor stride (ints) = 64 B padding
#define BIN_BLOCKS 256
#define EPB ((NE + BIN_BLOCKS - 1) / BIN_BLOCKS)   // 6250 edges per bin block

__device__ __forceinline__ float lrelu(float x) { return x >= 0.f ? x : 0.01f * x; }

// ------------------------------------------- projection + fused score tables
__global__ __launch_bounds__(256) void k_gemm_s(const float* __restrict__ h,
                                                const float* __restrict__ W,
                                                const float* __restrict__ a,
                                                __hip_bfloat16* __restrict__ zb,
                                                float* __restrict__ ssrc,
                                                float* __restrict__ sdst) {
    __shared__ float hs[64][65];
    __shared__ float ws[64][129];
    const int t  = threadIdx.x;
    const int n0 = blockIdx.x * 64;
    const int tx = t & 31;   // channel c = tx + 32*j (head j)
    const int ty = t >> 5;   // node n = ty + 8*i

    float acc[8][4];
#pragma unroll
    for (int i = 0; i < 8; ++i)
#pragma unroll
        for (int j = 0; j < 4; ++j) acc[i][j] = 0.f;

    for (int kt = 0; kt < IN_DIM; kt += 64) {
#pragma unroll
        for (int s = 0; s < 4; ++s) {
            const int idx4 = t + s * 256;
            const int n    = idx4 >> 4;
            const int kk   = (idx4 & 15) << 2;
            const int gn   = n0 + n;
            float4 v = make_float4(0.f, 0.f, 0.f, 0.f);
            if (gn < NN) v = *(const float4*)(h + (size_t)gn * IN_DIM + kt + kk);
            hs[kk + 0][n] = v.x; hs[kk + 1][n] = v.y;
            hs[kk + 2][n] = v.z; hs[kk + 3][n] = v.w;
        }
#pragma unroll
        for (int s = 0; s < 8; ++s) {
            const int idx4 = t + s * 256;
            const int c    = idx4 >> 4;
            const int kk   = (idx4 & 15) << 2;
            const float4 v = *(const float4*)(W + (size_t)c * IN_DIM + kt + kk);
            ws[kk + 0][c] = v.x; ws[kk + 1][c] = v.y;
            ws[kk + 2][c] = v.z; ws[kk + 3][c] = v.w;
        }
        __syncthreads();
#pragma unroll 4
        for (int k = 0; k < 64; ++k) {
            float wv[4], hv[8];
#pragma unroll
            for (int j = 0; j < 4; ++j) wv[j] = ws[k][tx + 32 * j];
#pragma unroll
            for (int i = 0; i < 8; ++i) hv[i] = hs[k][ty + 8 * i];
#pragma unroll
            for (int i = 0; i < 8; ++i)
#pragma unroll
                for (int j = 0; j < 4; ++j) acc[i][j] = fmaf(hv[i], wv[j], acc[i][j]);
        }
        __syncthreads();
    }
#pragma unroll
    for (int i = 0; i < 8; ++i) {
        const int gn = n0 + ty + 8 * i;
        if (gn < NN) {
#pragma unroll
            for (int j = 0; j < 4; ++j)
                zb[(size_t)gn * OC + tx + 32 * j] = __float2bfloat16(acc[i][j]);
        }
    }
    float as[4], ad[4];
#pragma unroll
    for (int j = 0; j < 4; ++j) {
        as[j] = a[j * 64 + tx];
        ad[j] = a[j * 64 + 32 + tx];
    }
#pragma unroll
    for (int i = 0; i < 8; ++i) {
        const int gn = n0 + ty + 8 * i;
#pragma unroll
        for (int j = 0; j < 4; ++j) {
            float ps = acc[i][j] * as[j];
            float pd = acc[i][j] * ad[j];
#pragma unroll
            for (int off = 16; off > 0; off >>= 1) {
                ps += __shfl_xor(ps, off);
                pd += __shfl_xor(pd, off);
            }
            if (tx == 0 && gn < NN) {
                ssrc[gn * 4 + j] = ps;
                sdst[gn * 4 + j] = pd;
            }
        }
    }
}

// ------------------------------------------------------ seed bucket cursors
__global__ __launch_bounds__(256) void k_init(int* __restrict__ cursor) {
    const int b = blockIdx.x * 256 + threadIdx.x;
    if (b < NBUCK) cursor[b * CURS] = b * CAP;
}

// ------------------- bin edges: LDS count -> per-(block,bucket) reserve -> scatter
__global__ __launch_bounds__(256) void k_bin2(const int* __restrict__ src,
                                              const int* __restrict__ dst,
                                              int* __restrict__ cursor,
                                              uint32_t* __restrict__ ebuf) {
    __shared__ int hb[NBUCK];
    __shared__ int ofs[NBUCK];
    const int t    = threadIdx.x;
    const int ebeg = blockIdx.x * EPB;
    const int eend = min(ebeg + EPB, NE);
    for (int i = t; i < NBUCK; i += 256) hb[i] = 0;
    __syncthreads();
    for (int e = ebeg + t; e < eend; e += 256)
        atomicAdd(&hb[dst[e] >> NBSH], 1);
    __syncthreads();
    for (int i = t; i < NBUCK; i += 256) {
        const int c = hb[i];
        ofs[i] = (c > 0) ? atomicAdd(&cursor[i * CURS], c) : 0;
        hb[i] = 0;
    }
    __syncthreads();
    for (int e = ebeg + t; e < eend; e += 256) {
        const int d = dst[e];
        const int b = d >> NBSH;
        const int p = ofs[b] + atomicAdd(&hb[b], 1);
        if (p < (b + 1) * CAP)   // defensive (statistically impossible overflow)
            ebuf[p] = (uint32_t)src[e] | ((uint32_t)(d & 63) << 16);
    }
}

// ---------------- per-bucket: LDS sort to per-node lists + register aggregate
// 512 threads (8 waves). Phase 1: count/scan/scatter the bucket's edges into
// per-node ushort lists in LDS. Phase 2: wave w processes nodes 8w..8w+7;
// per node: lane computes exp-weights (one edge/lane), stages {sid,w} in LDS,
// then 16-lane groups gather 4 z-rows/iter via dwordx4, register-accumulate.
__global__ __launch_bounds__(512) void k_gatb(const uint32_t* __restrict__ zb,
                                              const float4* __restrict__ ssrc,
                                              const float4* __restrict__ sdst,
                                              const int* __restrict__ cursor,
                                              const uint32_t* __restrict__ ebuf,
                                              float* __restrict__ out) {
    __shared__ unsigned short elist[CAP];   //  5120 B
    __shared__ float2 lp[8][64][4];         // 16384 B  [wave][edge][head]={sid,w}
    __shared__ float4 sdl[64];              //  1024 B
    __shared__ int cnt[64], cur[64], basel[64];
    const int b     = blockIdx.x;
    const int tid   = threadIdx.x;
    const int bbase = b * CAP;
    const int ecnt  = min(cursor[b * CURS], bbase + CAP) - bbase;

    if (tid < 64) cnt[tid] = 0;
    if (tid >= 64 && tid < 128) {
        const int gnode = (b << NBSH) + tid - 64;
        sdl[tid - 64] = (gnode < NN) ? sdst[gnode] : make_float4(0.f, 0.f, 0.f, 0.f);
    }
    __syncthreads();
    for (int i = tid; i < ecnt; i += 512)
        atomicAdd(&cnt[(ebuf[bbase + i] >> 16) & 63], 1);
    __syncthreads();
    if (tid < 64) {
        const int d = cnt[tid];
        int v = d;
#pragma unroll
        for (int off = 1; off < 64; off <<= 1) {
            const int u = __shfl_up(v, off);
            if (tid >= off) v += u;
        }
        basel[tid] = v - d;
        cur[tid]   = v - d;
    }
    __syncthreads();
    for (int i = tid; i < ecnt; i += 512) {
        const uint32_t v = ebuf[bbase + i];
        const int dl = (v >> 16) & 63;
        const int p  = atomicAdd(&cur[dl], 1);
        elist[p] = (unsigned short)(v & 0xffffu);
    }
    __syncthreads();

    // phase 2: one wave per node, 8 nodes per wave
    const int wid    = tid >> 6;
    const int lane   = tid & 63;
    const int lane16 = lane & 15;
    const int grp    = lane >> 4;
    const int hsel   = lane16 >> 2;
#pragma unroll 1
    for (int nl = wid * 8; nl < wid * 8 + 8; ++nl) {
        const int gnode = (b << NBSH) + nl;
        if (gnode >= NN) break;                 // wave-uniform
        const int d  = cnt[nl];
        const int s0 = basel[nl];
        const float4 sd = sdl[nl];

        float acc[8];
#pragma unroll
        for (int i = 0; i < 8; ++i) acc[i] = 0.f;
        float dn0 = 0.f, dn1 = 0.f, dn2 = 0.f, dn3 = 0.f;

        for (int base = 0; base < d; base += 64) {
            const int myj = base + lane;
            int sid_l = 0;
            float x0 = 0.f, x1 = 0.f, x2 = 0.f, x3 = 0.f;
            if (myj < d) {
                sid_l = elist[s0 + myj];
                const float4 ss = ssrc[sid_l];
                x0 = __expf(lrelu(ss.x + sd.x));
                x1 = __expf(lrelu(ss.y + sd.y));
                x2 = __expf(lrelu(ss.z + sd.z));
                x3 = __expf(lrelu(ss.w + sd.w));
                dn0 += x0; dn1 += x1; dn2 += x2; dn3 += x3;
            }
            const float sf = __builtin_bit_cast(float, sid_l);
            float4* lq = (float4*)&lp[wid][lane][0];
            lq[0] = make_float4(sf, x0, sf, x1);
            lq[1] = make_float4(sf, x2, sf, x3);

            const int cntc = min(64, d - base);
            const int nit  = (cntc + 3) >> 2;
#pragma unroll 2
            for (int it = 0; it < nit; ++it) {
                const int e4 = (it << 2) + grp;
                const float2 pw = lp[wid][e4][hsel];
                const int   sid = __builtin_bit_cast(int, pw.x);
                const float w   = pw.y;
                const uint4 Z = *(const uint4*)(zb + ((size_t)sid << 6) + (lane16 << 2));
                acc[0] = fmaf(w, __builtin_bit_cast(float, Z.x << 16),          acc[0]);
                acc[1] = fmaf(w, __builtin_bit_cast(float, Z.x & 0xffff0000u),  acc[1]);
                acc[2] = fmaf(w, __builtin_bit_cast(float, Z.y << 16),          acc[2]);
                acc[3] = fmaf(w, __builtin_bit_cast(float, Z.y & 0xffff0000u),  acc[3]);
                acc[4] = fmaf(w, __builtin_bit_cast(float, Z.z << 16),          acc[4]);
                acc[5] = fmaf(w, __builtin_bit_cast(float, Z.z & 0xffff0000u),  acc[5]);
                acc[6] = fmaf(w, __builtin_bit_cast(float, Z.w << 16),          acc[6]);
                acc[7] = fmaf(w, __builtin_bit_cast(float, Z.w & 0xffff0000u),  acc[7]);
            }
        }
#pragma unroll
        for (int i = 0; i < 8; ++i) {
            acc[i] += __shfl_xor(acc[i], 16);
            acc[i] += __shfl_xor(acc[i], 32);
        }
#pragma unroll
        for (int off = 32; off > 0; off >>= 1) {
            dn0 += __shfl_xor(dn0, off);
            dn1 += __shfl_xor(dn1, off);
            dn2 += __shfl_xor(dn2, off);
            dn3 += __shfl_xor(dn3, off);
        }
        const float dsel = (hsel == 0) ? dn0 : (hsel == 1) ? dn1 : (hsel == 2) ? dn2 : dn3;
        const float inv  = (dsel > 0.f) ? 1.0f / dsel : 0.f;
        if (grp == 0) {
            float* op = out + (size_t)gnode * OC + (lane16 << 3);
            *(float4*)(op)     = make_float4(acc[0]*inv, acc[1]*inv, acc[2]*inv, acc[3]*inv);
            *(float4*)(op + 4) = make_float4(acc[4]*inv, acc[5]*inv, acc[6]*inv, acc[7]*inv);
        }
    }
}

// ------------------------------------------------------------------- launcher
extern "C" void kernel_launch(void* const* d_in, const int* in_sizes, int n_in,
                              void* d_out, int out_size, void* d_ws, size_t ws_size,
                              hipStream_t stream) {
    const float* h_in = (const float*)d_in[0];
    const float* W    = (const float*)d_in[1];
    const float* a    = (const float*)d_in[2];
    const int*   src  = (const int*)d_in[3];
    const int*   dst  = (const int*)d_in[4];
    float*       out  = (float*)d_out;

    char* w = (char*)d_ws;
    __hip_bfloat16* zb = (__hip_bfloat16*)(w);          // 12,800,000 B
    float*    ssrc     = (float*)(w + 12800000);        //    800,000 B
    float*    sdst     = (float*)(w + 13600000);        //    800,000 B
    int*      cursor   = (int*)(w + 14400000);          //     50,048 B
    uint32_t* ebuf     = (uint32_t*)(w + 14450048);     //  8,007,680 B (782*2560*4)
    // total 22,457,728 B

    k_gemm_s<<<(NN + 63) / 64, 256, 0, stream>>>(h_in, W, a, zb, ssrc, sdst);
    k_init  <<<(NBUCK + 255) / 256, 256, 0, stream>>>(cursor);
    k_bin2  <<<BIN_BLOCKS, 256, 0, stream>>>(src, dst, cursor, ebuf);
    k_gatb  <<<NBUCK, 512, 0, stream>>>((const uint32_t*)zb,
                                        (const float4*)ssrc, (const float4*)sdst,
                                        cursor, ebuf, out);
}